// Round 7
// baseline (421.323 us; speedup 1.0000x reference)
//
#include <hip/hip_runtime.h>

// PointNet fused kernel for MI355X (gfx950) — round 7.
//
// Algebra: segment-MLP + cb are per-row constants -> cancel in the per-row
// min/max rescale. Only s1[m,n] = feat·cW[0:6] + relu(MLP3(feat))·cW[6:262]
// matters, then per-row rescale to [-1,1].
//
// Round-7: AGPR-pin the stationary weights. R5/R6 allocated only ~128 arch
// VGPRs (acc+bfr+w1r+temps) and left wA[8][4] (128 regs) in SCRATCH ->
// ~2.1 GB/dispatch of L2/L3 scratch reads, 377 us, MfmaUtil 15%.
// gfx950 MFMA operands are AV-class (VGPR or AGPR), so an empty inline asm
// with "+a" pins each weight fragment into the AGPR half of the unified
// register file; the MFMA builtin consumes it from AGPR directly, and the
// compiler keeps handling all hazards/waitcnts. AGPR=128 (wA), arch~120.
// Pipeline unchanged: 256 persistent blocks (1/CU), 8 waves:
//   waves 0-3 ("A"): W1+W2 slices in regs; per tile: feat->L1->h1->L2->h2
//   waves 4-7 ("B"): W3 slice in regs;     per tile: h2->L3->classifier->out
// Tiles (64 pts) stream through LDS; 3 barriers per beat, 34 beats.

typedef __attribute__((ext_vector_type(8))) short short8;   // 8 bf16
typedef __attribute__((ext_vector_type(4))) float f32x4;    // MFMA accum
typedef __attribute__((ext_vector_type(4))) unsigned int u32x4;

#define THREADS 512
#define NTILES 32          // tiles per block; 256 blocks x 32 = 8192 tiles

__device__ __forceinline__ unsigned short f2bf(float f) {
  union { float f; unsigned int u; } x; x.f = f;
  unsigned int r = x.u + 0x7fffu + ((x.u >> 16) & 1u);   // RNE
  return (unsigned short)(r >> 16);
}

__device__ __forceinline__ unsigned int cvt_pk_bf16(float lo, float hi) {
  unsigned int r;
  asm("v_cvt_pk_bf16_f32 %0, %1, %2" : "=v"(r) : "v"(lo), "v"(hi));
  return r;
}

// ---------------------------------------------------------------------------
// k0: pack weights into MFMA A-fragment order:
//   idx(s,ct,hi,col,j) = (((s*16+ct)*4+hi)*16+col)*8 + j
//   k = s*32 + hi*8 + j (zero past Kreal), c = ct*16 + col
// Regions (ushort): W1 @0 (8192), W2 @8192 (65536), W3 @73728 (65536)
// ---------------------------------------------------------------------------
__global__ void pn_pack(const float* __restrict__ W1,
                        const float* __restrict__ W2,
                        const float* __restrict__ W3,
                        unsigned short* __restrict__ wp) {
  int e = blockIdx.x * 256 + threadIdx.x;           // 0 .. 139263
  const float* src; int Kreal, base, r;
  if (e < 8192)       { src = W1; Kreal = 6;   base = 0;     r = e; }
  else if (e < 73728) { src = W2; Kreal = 256; base = 8192;  r = e - 8192; }
  else                { src = W3; Kreal = 256; base = 73728; r = e - 73728; }
  int j   = r & 7;
  int col = (r >> 3) & 15;
  int hi  = (r >> 7) & 3;
  int ct  = (r >> 9) & 15;
  int s   = r >> 13;
  int k = s * 32 + hi * 8 + j;
  int c = ct * 16 + col;
  float v = (k < Kreal) ? src[k * 256 + c] : 0.0f;
  wp[base + r] = f2bf(v);
}

// ---------------------------------------------------------------------------
// helpers: per-wave output tile = 64 channels x 64 points
// ---------------------------------------------------------------------------
__device__ __forceinline__ void acc_init(f32x4 (&acc)[4][4], const float* bv,
                                         int cgrp, int hi) {
#pragma unroll
  for (int cf = 0; cf < 4; ++cf) {
    f32x4 bi = *(const f32x4*)(bv + cgrp * 64 + cf * 16 + hi * 4);
#pragma unroll
    for (int pf = 0; pf < 4; ++pf) acc[cf][pf] = bi;
  }
}

// GEMM with AGPR-resident A (weights) and LDS B (h, swizzled)
__device__ __forceinline__ void gemm256r(const short8 (&wA)[8][4],
                                         const unsigned short* hbuf,
                                         int l15, int hi,
                                         f32x4 (&acc)[4][4]) {
#pragma unroll
  for (int ks = 0; ks < 8; ++ks) {
    short8 bfr[4];
#pragma unroll
    for (int pf = 0; pf < 4; ++pf) {
      int p = pf * 16 + l15;
      int byteoff = ((p * 256 + ks * 32 + hi * 8) * 2) ^ ((p & 7) << 4);
      bfr[pf] = *(const short8*)((const char*)hbuf + byteoff);
    }
#pragma unroll
    for (int cf = 0; cf < 4; ++cf)
#pragma unroll
      for (int pf = 0; pf < 4; ++pf)
        acc[cf][pf] = __builtin_amdgcn_mfma_f32_16x16x32_bf16(
            wA[ks][cf], bfr[pf], acc[cf][pf], 0, 0, 0);
  }
}

// relu -> bf16 (cvt_pk) -> swizzled h buffer, b64 writes (bias already in acc)
__device__ __forceinline__ void epi_h(f32x4 (&acc)[4][4], unsigned short* dst,
                                      int cgrp, int l15, int hi) {
#pragma unroll
  for (int cf = 0; cf < 4; ++cf) {
    int c0 = cgrp * 64 + cf * 16 + hi * 4;
#pragma unroll
    for (int pf = 0; pf < 4; ++pf) {
      int p = pf * 16 + l15;
      f32x4 a = acc[cf][pf];
      unsigned int lo  = cvt_pk_bf16(fmaxf(a[0], 0.0f), fmaxf(a[1], 0.0f));
      unsigned int hi2 = cvt_pk_bf16(fmaxf(a[2], 0.0f), fmaxf(a[3], 0.0f));
      unsigned long long w = (unsigned long long)lo | ((unsigned long long)hi2 << 32);
      int byteoff = ((p * 256 + c0) * 2) ^ ((p & 7) << 4);
      *(unsigned long long*)((char*)dst + byteoff) = w;
    }
  }
}

// ---------------------------------------------------------------------------
// k1: persistent pipelined kernel. 256 blocks, 8 waves, 1 block/CU.
// Beat t: segA { A: feat/hF/fdot(t)        | B(w4): out(t-2) }  bar
//         segB { A: L1(t) -> h1            | B: -            }  bar
//         segC { A: L2(t) -> h2[t&1]       | B: L3(t-1)+tail }  bar
// ---------------------------------------------------------------------------
__global__ __launch_bounds__(THREADS, 1) void pn_pipe(
    const float* __restrict__ feat,
    const unsigned short* __restrict__ wp,
    const float* __restrict__ b1,
    const float* __restrict__ b2,
    const float* __restrict__ b3,
    const float* __restrict__ cW,
    float* __restrict__ out) {
  __shared__ unsigned short h1[64 * 256];      // 32 KB swizzled
  __shared__ unsigned short h2[2][64 * 256];   // 64 KB swizzled ping-pong
  __shared__ unsigned short hF[64 * 8];        // 1 KB layer-1 B slice
  __shared__ float biasL[3 * 256];             // 3 KB
  __shared__ float whL[256];                   // 1 KB (cW[6..261])
  __shared__ float fdA[4][64];                 // 1 KB fdot relay
  __shared__ float sPart[4][64];               // 1 KB tail partials

  const int tid  = threadIdx.x;
  const int lane = tid & 63;
  const int wave = tid >> 6;
  const int l15  = lane & 15;
  const int hi   = lane >> 4;
  const bool isA = wave < 4;
  const int cgrp = wave & 3;

  if (tid < 256) {
    biasL[tid]       = b1[tid];
    biasL[256 + tid] = b2[tid];
    biasL[512 + tid] = b3[tid];
    whL[tid]         = cW[6 + tid];
  }
  // classifier feat weights (uniform -> SGPR)
  const float c0 = cW[0], c1 = cW[1], c2 = cW[2], c3 = cW[3], c4 = cW[4], c5 = cW[5];

  // ---- stationary weights -> registers, PINNED INTO AGPRs (once per block)
  short8 wA[8][4];            // A-waves: W2 slice; B-waves: W3 slice (128 AGPR)
  {
    const unsigned short* wb = wp + (isA ? 8192 : 73728);
#pragma unroll
    for (int ks = 0; ks < 8; ++ks)
#pragma unroll
      for (int cf = 0; cf < 4; ++cf) {
        wA[ks][cf] = *(const short8*)(wb + (((((ks * 16 + (cgrp * 4 + cf)) * 4) + hi) * 16 + l15) << 3));
        asm("" : "+a"(wA[ks][cf]));   // pin fragment into AGPRs
      }
  }
  short8 w1r[4];              // W1 slice (A uses; 16 VGPR)
#pragma unroll
  for (int cf = 0; cf < 4; ++cf)
    w1r[cf] = *(const short8*)(wp + ((((cgrp * 4 + cf) * 4 + hi) * 16 + l15) << 3));

  const int tbase = blockIdx.x * NTILES;
  const short8 zero8 = {0, 0, 0, 0, 0, 0, 0, 0};
  f32x4 acc[4][4];

  __syncthreads();   // biasL/whL visible

#pragma unroll 1
  for (int t = 0; t <= NTILES + 1; ++t) {
    // ---------------- segA ----------------
    if (isA) {
      if (t < NTILES && tid < 64) {
        int g  = tbase + t;
        int g0 = ((g >> 7) << 13) + ((g & 127) << 6);
        const float* fp = feat + (size_t)(g0 + tid) * 6;
        float f0 = fp[0], f1 = fp[1], f2 = fp[2], f3 = fp[3], f4 = fp[4], f5 = fp[5];
        fdA[t & 3][tid] = f0 * c0 + f1 * c1 + f2 * c2 + f3 * c3 + f4 * c4 + f5 * c5;
        u32x4 v;
        v[0] = cvt_pk_bf16(f0, f1);
        v[1] = cvt_pk_bf16(f2, f3);
        v[2] = cvt_pk_bf16(f4, f5);
        v[3] = 0;
        *(u32x4*)(hF + tid * 8) = v;
      }
    } else if (wave == 4 && t >= 2) {
      int g  = tbase + (t - 2);
      int g0 = ((g >> 7) << 13) + ((g & 127) << 6);
      float s = sPart[0][lane] + sPart[1][lane] + sPart[2][lane] + sPart[3][lane]
              + fdA[(t - 2) & 3][lane];
      out[g0 + lane] = s;     // raw s1; rescaled by pn_finalize
    }
    __syncthreads();

    // ---------------- segB: A: layer 1 ----------------
    if (isA && t < NTILES) {
      acc_init(acc, biasL, cgrp, hi);
#pragma unroll
      for (int pf = 0; pf < 4; ++pf) {
        int p = pf * 16 + l15;
        short8 b = (hi == 0) ? *(const short8*)(hF + p * 8) : zero8;
#pragma unroll
        for (int cf = 0; cf < 4; ++cf)
          acc[cf][pf] = __builtin_amdgcn_mfma_f32_16x16x32_bf16(
              w1r[cf], b, acc[cf][pf], 0, 0, 0);
      }
      epi_h(acc, h1, cgrp, l15, hi);
    }
    __syncthreads();

    // ---------------- segC ----------------
    if (isA) {
      if (t < NTILES) {
        acc_init(acc, biasL + 256, cgrp, hi);
        gemm256r(wA, h1, l15, hi, acc);
        epi_h(acc, h2[t & 1], cgrp, l15, hi);
      }
    } else if (t >= 1 && t <= NTILES) {
      acc_init(acc, biasL + 512, cgrp, hi);
      gemm256r(wA, h2[(t - 1) & 1], l15, hi, acc);
      float part[4] = {0.f, 0.f, 0.f, 0.f};
#pragma unroll
      for (int cf = 0; cf < 4; ++cf) {
        int c0c = cgrp * 64 + cf * 16 + hi * 4;
#pragma unroll
        for (int r = 0; r < 4; ++r) {
          float wv = whL[c0c + r];
#pragma unroll
          for (int pf = 0; pf < 4; ++pf)
            part[pf] += fmaxf(acc[cf][pf][r], 0.0f) * wv;
        }
      }
#pragma unroll
      for (int off = 16; off < 64; off <<= 1)
#pragma unroll
        for (int pf = 0; pf < 4; ++pf)
          part[pf] += __shfl_xor(part[pf], off);
      if (hi == 0) {
#pragma unroll
        for (int pf = 0; pf < 4; ++pf)
          sPart[cgrp][pf * 16 + l15] = part[pf];
      }
    }
    __syncthreads();
  }
}

// ---------------------------------------------------------------------------
// k2: per-bbox min/max rescale to [-1,1], in place.
// ---------------------------------------------------------------------------
__global__ void pn_finalize(float* __restrict__ out) {
  __shared__ float smn[4], smx[4];
  int mrow = blockIdx.x;
  float* row = out + mrow * 8192;
  float v[32];
  float mn = 1e30f, mx = -1e30f;
#pragma unroll
  for (int i = 0; i < 32; ++i) {
    v[i] = row[threadIdx.x + i * 256];
    mn = fminf(mn, v[i]);
    mx = fmaxf(mx, v[i]);
  }
#pragma unroll
  for (int off = 1; off < 64; off <<= 1) {
    mn = fminf(mn, __shfl_xor(mn, off));
    mx = fmaxf(mx, __shfl_xor(mx, off));
  }
  int w = threadIdx.x >> 6;
  if ((threadIdx.x & 63) == 0) { smn[w] = mn; smx[w] = mx; }
  __syncthreads();
  mn = fminf(fminf(smn[0], smn[1]), fminf(smn[2], smn[3]));
  mx = fmaxf(fmaxf(smx[0], smx[1]), fmaxf(smx[2], smx[3]));
  float sc = 2.0f / (mx - mn);
#pragma unroll
  for (int i = 0; i < 32; ++i)
    row[threadIdx.x + i * 256] = (v[i] - mn) * sc - 1.0f;
}

// ---------------------------------------------------------------------------
extern "C" void kernel_launch(void* const* d_in, const int* in_sizes, int n_in,
                              void* d_out, int out_size, void* d_ws, size_t ws_size,
                              hipStream_t stream) {
  const float* feat = (const float*)d_in[0];
  const float* eW1  = (const float*)d_in[1];
  const float* eb1  = (const float*)d_in[2];
  const float* eW2  = (const float*)d_in[3];
  const float* eb2  = (const float*)d_in[4];
  const float* eW3  = (const float*)d_in[5];
  const float* eb3  = (const float*)d_in[6];
  // sW*/sb* (7..12) and cb (14) cancel in the per-row rescale -- unused.
  const float* cW   = (const float*)d_in[13];
  float* out = (float*)d_out;
  unsigned short* wpack = (unsigned short*)d_ws;   // 278,528 B of ws

  pn_pack<<<544, 256, 0, stream>>>(eW1, eW2, eW3, wpack);
  pn_pipe<<<256, THREADS, 0, stream>>>(feat, wpack, eb1, eb2, eb3, cW, out);
  pn_finalize<<<64, 256, 0, stream>>>(out);
}

// Round 8
// 150.273 us; speedup vs baseline: 2.8037x; 2.8037x over previous
//
#include <hip/hip_runtime.h>

// PointNet fused kernel for MI355X (gfx950) — round 8.
//
// Algebra: segment-MLP + cb are per-row constants -> cancel in the per-row
// min/max rescale. Only s1[m,n] = feat·cW[0:6] + relu(MLP3(feat))·cW[6:262]
// matters, then per-row rescale to [-1,1].
//
// Round-8: revert to the round-4 structure (64-pt blocks, 4 waves, 37 KB
// LDS, 92 VGPR — the best stable variant, 160 us) and software-pipeline the
// L2 weight fetches inside the GEMM: 3-buffer rotation, loads issued 2
// ks-steps ahead, so the ~300-cy L2 latency hides under the previous step's
// LDS reads + 16 MFMAs. +32 VGPR (target ~124, below the 128 allocation
// cliff that killed rounds 5-7's register-stationary attempts).

typedef __attribute__((ext_vector_type(8))) short short8;   // 8 bf16
typedef __attribute__((ext_vector_type(4))) float f32x4;    // MFMA accum
typedef __attribute__((ext_vector_type(4))) unsigned int u32x4;

#define THREADS 256

__device__ __forceinline__ unsigned short f2bf(float f) {
  union { float f; unsigned int u; } x; x.f = f;
  unsigned int r = x.u + 0x7fffu + ((x.u >> 16) & 1u);   // RNE
  return (unsigned short)(r >> 16);
}

__device__ __forceinline__ unsigned int cvt_pk_bf16(float lo, float hi) {
  unsigned int r;
  asm("v_cvt_pk_bf16_f32 %0, %1, %2" : "=v"(r) : "v"(lo), "v"(hi));
  return r;
}

// ---------------------------------------------------------------------------
// k0: pack weights into MFMA A-fragment order:
//   idx(s,ct,hi,col,j) = (((s*16+ct)*4+hi)*16+col)*8 + j
//   k = s*32 + hi*8 + j (zero past Kreal), c = ct*16 + col
// Regions (ushort): W1 @0 (8192), W2 @8192 (65536), W3 @73728 (65536)
// ---------------------------------------------------------------------------
__global__ void pn_pack(const float* __restrict__ W1,
                        const float* __restrict__ W2,
                        const float* __restrict__ W3,
                        unsigned short* __restrict__ wp) {
  int e = blockIdx.x * 256 + threadIdx.x;           // 0 .. 139263
  const float* src; int Kreal, base, r;
  if (e < 8192)       { src = W1; Kreal = 6;   base = 0;     r = e; }
  else if (e < 73728) { src = W2; Kreal = 256; base = 8192;  r = e - 8192; }
  else                { src = W3; Kreal = 256; base = 73728; r = e - 73728; }
  int j   = r & 7;
  int col = (r >> 3) & 15;
  int hi  = (r >> 7) & 3;
  int ct  = (r >> 9) & 15;
  int s   = r >> 13;
  int k = s * 32 + hi * 8 + j;
  int c = ct * 16 + col;
  float v = (k < Kreal) ? src[k * 256 + c] : 0.0f;
  wp[base + r] = f2bf(v);
}

// ---------------------------------------------------------------------------
// k1 helpers. Per wave: 64 channels (cgrp=wave) x 64 points (pf 0..3).
// ---------------------------------------------------------------------------
__device__ __forceinline__ short8 wload(const unsigned short* __restrict__ wpL,
                                        int ks, int ct, int hi, int l15) {
  return *(const short8*)(wpL + (((((ks * 16 + ct) * 4) + hi) * 16 + l15) << 3));
}

// GEMM, K=256: weight loads software-pipelined 2 ks-steps ahead (3-buf rot).
__device__ __forceinline__ void gemm256(const unsigned short* __restrict__ wpL,
                                        const unsigned short* hbuf,
                                        int cgrp, int l15, int hi,
                                        f32x4 (&acc)[4][4]) {
  short8 wbuf[3][4];
  // prologue: issue ks=0 and ks=1 loads
#pragma unroll
  for (int cf = 0; cf < 4; ++cf)
    wbuf[0][cf] = wload(wpL, 0, cgrp * 4 + cf, hi, l15);
#pragma unroll
  for (int cf = 0; cf < 4; ++cf)
    wbuf[1][cf] = wload(wpL, 1, cgrp * 4 + cf, hi, l15);

#pragma unroll
  for (int ks = 0; ks < 8; ++ks) {
    if (ks + 2 < 8) {
#pragma unroll
      for (int cf = 0; cf < 4; ++cf)
        wbuf[(ks + 2) % 3][cf] = wload(wpL, ks + 2, cgrp * 4 + cf, hi, l15);
    }
    short8 bfr[4];
#pragma unroll
    for (int pf = 0; pf < 4; ++pf) {               // B = h fragments (LDS, swz)
      int p = pf * 16 + l15;
      int byteoff = ((p * 256 + ks * 32 + hi * 8) * 2) ^ ((p & 7) << 4);
      bfr[pf] = *(const short8*)((const char*)hbuf + byteoff);
    }
#pragma unroll
    for (int cf = 0; cf < 4; ++cf)
#pragma unroll
      for (int pf = 0; pf < 4; ++pf)
        acc[cf][pf] = __builtin_amdgcn_mfma_f32_16x16x32_bf16(
            wbuf[ks % 3][cf], bfr[pf], acc[cf][pf], 0, 0, 0);
  }
}

// init acc with per-channel bias (broadcast over points)
__device__ __forceinline__ void acc_init(f32x4 (&acc)[4][4], const float* bv,
                                         int cgrp, int hi) {
#pragma unroll
  for (int cf = 0; cf < 4; ++cf) {
    f32x4 bi = *(const f32x4*)(bv + cgrp * 64 + cf * 16 + hi * 4);
#pragma unroll
    for (int pf = 0; pf < 4; ++pf) acc[cf][pf] = bi;
  }
}

// relu -> bf16 (cvt_pk) -> swizzled h buffer, b64 writes (bias already in acc)
__device__ __forceinline__ void epi_h(f32x4 (&acc)[4][4], unsigned short* dst,
                                      int cgrp, int l15, int hi) {
#pragma unroll
  for (int cf = 0; cf < 4; ++cf) {
    int c0 = cgrp * 64 + cf * 16 + hi * 4;         // 4 consecutive channels
#pragma unroll
    for (int pf = 0; pf < 4; ++pf) {
      int p = pf * 16 + l15;
      f32x4 a = acc[cf][pf];
      unsigned int lo  = cvt_pk_bf16(fmaxf(a[0], 0.0f), fmaxf(a[1], 0.0f));
      unsigned int hi2 = cvt_pk_bf16(fmaxf(a[2], 0.0f), fmaxf(a[3], 0.0f));
      unsigned long long w = (unsigned long long)lo | ((unsigned long long)hi2 << 32);
      int byteoff = ((p * 256 + c0) * 2) ^ ((p & 7) << 4);
      *(unsigned long long*)((char*)dst + byteoff) = w;
    }
  }
}

// ---------------------------------------------------------------------------
// k1: one block = 64 points of one bbox row; 4 waves; ~37 KB LDS.
// ---------------------------------------------------------------------------
__global__ __launch_bounds__(THREADS, 1) void pn_main(
    const float* __restrict__ feat,
    const unsigned short* __restrict__ wp,
    const float* __restrict__ b1,
    const float* __restrict__ b2,
    const float* __restrict__ b3,
    const float* __restrict__ cW,
    float* __restrict__ out) {
  __shared__ unsigned short hA[64 * 256];    // 32 KB, swizzled bf16 h (in-place)
  __shared__ unsigned short hF[64 * 8];      // 1 KB: layer-1 B slice (k0..7)
  __shared__ float biasL[3 * 256];           // 3 KB
  __shared__ float whL[256];                 // 1 KB (cW[6..261])
  float* sPart = (float*)hF;                 // overlay: hF dead after L1 gemm

  const int tid  = threadIdx.x;
  const int lane = tid & 63;
  const int wave = tid >> 6;
  const int l15  = lane & 15;
  const int hi   = lane >> 4;
  const int cgrp = wave;         // channel group (64 of 256)

  const int blk = blockIdx.x;
  const int m   = blk >> 7;                  // 128 blocks per bbox row
  const int n0  = (blk & 127) << 6;
  const int g0  = m * 8192 + n0;

  // ---- stage biases + classifier hidden weights
  biasL[tid]       = b1[tid & 255];
  biasL[256 + tid] = b2[tid & 255];
  biasL[512 + tid] = b3[tid & 255];
  whL[tid & 255]   = cW[6 + (tid & 255)];

  // ---- build hF (k0..7 slice, 2 zeros) + fdot in register
  float fdot = 0.0f;
  if (tid < 64) {
    const float* fp = feat + (g0 + tid) * 6;
    float f0 = fp[0], f1 = fp[1], f2 = fp[2], f3 = fp[3], f4 = fp[4], f5 = fp[5];
    fdot = f0 * cW[0] + f1 * cW[1] + f2 * cW[2] + f3 * cW[3] + f4 * cW[4] + f5 * cW[5];
    u32x4 v;
    v[0] = cvt_pk_bf16(f0, f1);
    v[1] = cvt_pk_bf16(f2, f3);
    v[2] = cvt_pk_bf16(f4, f5);
    v[3] = 0;
    *(u32x4*)(hF + tid * 8) = v;
  }
  __syncthreads();

  f32x4 acc[4][4];
  const short8 zero8 = {0, 0, 0, 0, 0, 0, 0, 0};

  // ---- layer 1 (K padded to 32; only hi==0 k-slots are nonzero)
  acc_init(acc, biasL + 0, cgrp, hi);
  {
    short8 afr[4], bfr[4];
#pragma unroll
    for (int cf = 0; cf < 4; ++cf) {
      int ct = cgrp * 4 + cf;
      afr[cf] = *(const short8*)(wp + (((ct * 4 + hi) * 16 + l15) << 3));
    }
#pragma unroll
    for (int pf = 0; pf < 4; ++pf) {
      int p = pf * 16 + l15;
      bfr[pf] = (hi == 0) ? *(const short8*)(hF + p * 8) : zero8;
    }
#pragma unroll
    for (int cf = 0; cf < 4; ++cf)
#pragma unroll
      for (int pf = 0; pf < 4; ++pf)
        acc[cf][pf] = __builtin_amdgcn_mfma_f32_16x16x32_bf16(
            afr[cf], bfr[pf], acc[cf][pf], 0, 0, 0);
  }
  epi_h(acc, hA, cgrp, l15, hi);
  __syncthreads();

  // ---- layer 2 (reads hA, writes hA in place after a barrier)
  acc_init(acc, biasL + 256, cgrp, hi);
  gemm256(wp + 8192, hA, cgrp, l15, hi, acc);
  __syncthreads();                       // all h1 reads complete
  epi_h(acc, hA, cgrp, l15, hi);
  __syncthreads();                       // h2 visible

  // ---- layer 3 + classifier dot
  acc_init(acc, biasL + 512, cgrp, hi);
  gemm256(wp + 73728, hA, cgrp, l15, hi, acc);

  float part[4] = {0.f, 0.f, 0.f, 0.f};
#pragma unroll
  for (int cf = 0; cf < 4; ++cf) {
    int c0 = cgrp * 64 + cf * 16 + hi * 4;
#pragma unroll
    for (int r = 0; r < 4; ++r) {
      float wv = whL[c0 + r];
#pragma unroll
      for (int pf = 0; pf < 4; ++pf)
        part[pf] += fmaxf(acc[cf][pf][r], 0.0f) * wv;
    }
  }
  // reduce across hi groups (same point, different channels)
#pragma unroll
  for (int off = 16; off < 64; off <<= 1)
#pragma unroll
    for (int pf = 0; pf < 4; ++pf)
      part[pf] += __shfl_xor(part[pf], off);
  if (hi == 0) {
#pragma unroll
    for (int pf = 0; pf < 4; ++pf)
      sPart[cgrp * 64 + pf * 16 + l15] = part[pf];
  }
  __syncthreads();

  if (tid < 64) {
    float s = sPart[tid] + sPart[64 + tid] + sPart[128 + tid] + sPart[192 + tid]
            + fdot;
    out[g0 + tid] = s;   // raw s1; rescaled by pn_finalize
  }
}

// ---------------------------------------------------------------------------
// k2: per-bbox min/max rescale to [-1,1], in place.
// ---------------------------------------------------------------------------
__global__ void pn_finalize(float* __restrict__ out) {
  __shared__ float smn[4], smx[4];
  int mrow = blockIdx.x;
  float* row = out + mrow * 8192;
  float v[32];
  float mn = 1e30f, mx = -1e30f;
#pragma unroll
  for (int i = 0; i < 32; ++i) {
    v[i] = row[threadIdx.x + i * 256];
    mn = fminf(mn, v[i]);
    mx = fmaxf(mx, v[i]);
  }
#pragma unroll
  for (int off = 1; off < 64; off <<= 1) {
    mn = fminf(mn, __shfl_xor(mn, off));
    mx = fmaxf(mx, __shfl_xor(mx, off));
  }
  int w = threadIdx.x >> 6;
  if ((threadIdx.x & 63) == 0) { smn[w] = mn; smx[w] = mx; }
  __syncthreads();
  mn = fminf(fminf(smn[0], smn[1]), fminf(smn[2], smn[3]));
  mx = fmaxf(fmaxf(smx[0], smx[1]), fmaxf(smx[2], smx[3]));
  float sc = 2.0f / (mx - mn);
#pragma unroll
  for (int i = 0; i < 32; ++i)
    row[threadIdx.x + i * 256] = (v[i] - mn) * sc - 1.0f;
}

// ---------------------------------------------------------------------------
extern "C" void kernel_launch(void* const* d_in, const int* in_sizes, int n_in,
                              void* d_out, int out_size, void* d_ws, size_t ws_size,
                              hipStream_t stream) {
  const float* feat = (const float*)d_in[0];
  const float* eW1  = (const float*)d_in[1];
  const float* eb1  = (const float*)d_in[2];
  const float* eW2  = (const float*)d_in[3];
  const float* eb2  = (const float*)d_in[4];
  const float* eW3  = (const float*)d_in[5];
  const float* eb3  = (const float*)d_in[6];
  // sW*/sb* (7..12) and cb (14) cancel in the per-row rescale -- unused.
  const float* cW   = (const float*)d_in[13];
  float* out = (float*)d_out;
  unsigned short* wpack = (unsigned short*)d_ws;   // 278,528 B of ws

  pn_pack<<<544, 256, 0, stream>>>(eW1, eW2, eW3, wpack);
  pn_main<<<8192, THREADS, 0, stream>>>(feat, wpack, eb1, eb2, eb3, cW, out);
  pn_finalize<<<64, 256, 0, stream>>>(out);
}